// Round 8
// baseline (408.526 us; speedup 1.0000x reference)
//
#include <hip/hip_runtime.h>
#include <hip/hip_bf16.h>

#define NN 32768
#define EE 524288
#define GG 512

typedef __bf16 bf16x8 __attribute__((ext_vector_type(8)));
typedef float  f32x4  __attribute__((ext_vector_type(4)));

static __device__ __forceinline__ float bf2f(unsigned short u) {
    union { unsigned int i; float f; } v; v.i = ((unsigned int)u) << 16; return v.f;
}
static __device__ __forceinline__ unsigned short f2bf(float f) {
    __bf16 b = (__bf16)f;
    return __builtin_bit_cast(unsigned short, b);
}
static __device__ __forceinline__ unsigned int pk2(float a, float b) {
    return (unsigned int)f2bf(a) | ((unsigned int)f2bf(b) << 16);
}
static __device__ __forceinline__ void fma8(float* a, float w, uint4 hv) {
    a[0] += w * bf2f((unsigned short)(hv.x & 0xffff));
    a[1] += w * bf2f((unsigned short)(hv.x >> 16));
    a[2] += w * bf2f((unsigned short)(hv.y & 0xffff));
    a[3] += w * bf2f((unsigned short)(hv.y >> 16));
    a[4] += w * bf2f((unsigned short)(hv.z & 0xffff));
    a[5] += w * bf2f((unsigned short)(hv.z >> 16));
    a[6] += w * bf2f((unsigned short)(hv.w & 0xffff));
    a[7] += w * bf2f((unsigned short)(hv.w >> 16));
}
static __device__ __forceinline__ void fma4(float* a, float w, uint2 hv) {
    a[0] += w * bf2f((unsigned short)(hv.x & 0xffff));
    a[1] += w * bf2f((unsigned short)(hv.x >> 16));
    a[2] += w * bf2f((unsigned short)(hv.y & 0xffff));
    a[3] += w * bf2f((unsigned short)(hv.y >> 16));
}

// ---------------- fused prep: edge count + weight convert + x convert ----------------
struct WJob { const float* in; unsigned short* out; int K; };
struct WJobs { WJob j[10]; };

__global__ __launch_bounds__(256) void prep_kernel(WJobs jobs, const int* __restrict__ src,
                                                   int* __restrict__ cnt,
                                                   const float* __restrict__ x,
                                                   unsigned short* __restrict__ xb) {
    if (blockIdx.x < 2048) {
        int e = blockIdx.x * 256 + threadIdx.x;
        atomicAdd(&cnt[src[e]], 1);
    } else if (blockIdx.x < 2088) {
        int b = blockIdx.x - 2048;
        WJob jb = jobs.j[b >> 2];
        int quarter = b & 3;
        int per = jb.K * 128 / 4;
        for (int idx = quarter * per + threadIdx.x; idx < (quarter + 1) * per; idx += 256) {
            int k = idx >> 7, c = idx & 127;
            jb.out[c * jb.K + k] = f2bf(jb.in[idx]);
        }
    } else {
        int b2 = blockIdx.x - 2088;            // 512 blocks, N*64 = 2M elements
        int base = b2 * 4096 + threadIdx.x;
        #pragma unroll
        for (int k = 0; k < 16; ++k) {
            int idx = base + k * 256;
            xb[idx] = f2bf(x[idx]);
        }
    }
}

// single block, 1024 threads; writes row_start AND cursor
__global__ void scan_kernel(const int* __restrict__ cnt, int* __restrict__ row_start,
                            int* __restrict__ cursor) {
    int tid = threadIdx.x;
    int base = tid * 32;
    int vals[32];
    int s = 0;
    #pragma unroll
    for (int i = 0; i < 32; ++i) { vals[i] = cnt[base + i]; s += vals[i]; }
    int lane = tid & 63, wave = tid >> 6;
    int incl = s;
    #pragma unroll
    for (int off = 1; off < 64; off <<= 1) {
        int t = __shfl_up(incl, off);
        if (lane >= off) incl += t;
    }
    __shared__ int wave_tot[16];
    if (lane == 63) wave_tot[wave] = incl;
    __syncthreads();
    int wave_base = 0;
    for (int w = 0; w < wave; ++w) wave_base += wave_tot[w];
    int run = wave_base + incl - s;
    #pragma unroll
    for (int i = 0; i < 32; ++i) {
        row_start[base + i] = run;
        cursor[base + i] = run;
        run += vals[i];
    }
    if (tid == 1023) row_start[NN] = run;
}

// packed CSR entry: low16 = dst node (<32768), high16 = bf16(edge weight)
__global__ void fill_kernel(const int* __restrict__ src, const int* __restrict__ dst,
                            const float* __restrict__ w,
                            int* __restrict__ cursor, unsigned int* __restrict__ csr) {
    int e = blockIdx.x * 256 + threadIdx.x;
    if (e < EE) {
        int s = src[e];
        int p = atomicAdd(&cursor[s], 1);
        csr[p] = (unsigned int)dst[e] | ((unsigned int)f2bf(w[e]) << 16);
    }
}

// ---------------- fused GIN layer: gather + GEMM1 + GEMM2 + BN + pool ----------------
// 2048 blocks x 256 thr (4 waves). Block owns 16 nodes/rows.
// Block's csr segment (contiguous!) staged in LDS; gather reads entries via LDS broadcast.
// Gather: wave w handles nodes w*4..w*4+3; 4 concurrent 16-lane edge streams, unroll-2.
// GEMM: wave w computes cols w*32..w*32+31 over all 16 rows.
template<bool FIRST, bool LAST>
__global__ __launch_bounds__(256) void layer_kernel(
        const unsigned short* __restrict__ h_in,  // bf16: [N][64] if FIRST else [N][128]
        const int* __restrict__ row_start,
        const unsigned int* __restrict__ csr,
        const unsigned short* __restrict__ W1t,   // [128][K1] bf16
        const float* __restrict__ b1,
        const unsigned short* __restrict__ W2t,   // [128][128] bf16
        const float* __restrict__ b2,
        const float* __restrict__ g, const float* __restrict__ be,
        const float* __restrict__ m, const float* __restrict__ v,
        const int* __restrict__ gidx,
        unsigned short* __restrict__ h_out,       // [N][128] bf16 bn'd (unused if LAST)
        float* __restrict__ pools, int col_off) {

    constexpr int K1 = FIRST ? 64 : 128;
    constexpr int KS1 = K1 / 32;
    constexpr int CH = FIRST ? 4 : 8;

    __shared__ unsigned int smem[2176];       // A1[16][68] | T[16][68]; OUT[16][132] overlays
    __shared__ unsigned int scsr[2048];
    __shared__ float sscale[128], sshift[128];
    __shared__ int srow[17];
    __shared__ int sgid[16];

    unsigned int* A1 = smem;
    unsigned int* T  = smem + 16 * 68;
    float* OUT = (float*)smem;

    int tid = threadIdx.x;
    int wave = tid >> 6, lane = tid & 63;
    int grp = lane >> 4, sub = lane & 15;     // gather roles
    int mrow = lane & 15, quad = lane >> 4;   // mfma roles

    if (tid < 128) {
        float sc = g[tid] * rsqrtf(v[tid] + 1e-3f);
        sscale[tid] = sc;
        sshift[tid] = be[tid] - m[tid] * sc;
    } else if (tid < 144) {
        sgid[tid - 128] = gidx[blockIdx.x * 16 + (tid - 128)];
    } else if (tid < 161) {
        srow[tid - 144] = row_start[blockIdx.x * 16 + (tid - 144)];
    }

    int seg_s = row_start[blockIdx.x * 16];
    int seg_e = row_start[blockIdx.x * 16 + 16];
    int staged = seg_e - seg_s; if (staged > 2048) staged = 2048;
    for (int p = tid; p < staged; p += 256) scsr[p] = csr[seg_s + p];
    __syncthreads();

    // ---- gather into A1 ----
    for (int i = 0; i < 4; ++i) {
        int r = wave * 4 + i;
        int ls = srow[r] - seg_s, le = srow[r + 1] - seg_s;
        float accA[CH], accB[CH];
        #pragma unroll
        for (int c = 0; c < CH; ++c) { accA[c] = 0.f; accB[c] = 0.f; }

        if (FIRST) {
            const uint2* hp = (const uint2*)h_in;
            int p = ls + grp;
            if (le <= staged) {
                for (; p + 4 < le; p += 8) {
                    unsigned int ea = scsr[p], eb = scsr[p + 4];
                    uint2 ha = hp[(ea & 0xffffu) * 16 + sub];
                    uint2 hb = hp[(eb & 0xffffu) * 16 + sub];
                    fma4(accA, bf2f((unsigned short)(ea >> 16)), ha);
                    fma4(accB, bf2f((unsigned short)(eb >> 16)), hb);
                }
                if (p < le) {
                    unsigned int ea = scsr[p];
                    fma4(accA, bf2f((unsigned short)(ea >> 16)), hp[(ea & 0xffffu) * 16 + sub]);
                }
            } else {
                for (; p < le; p += 4) {
                    unsigned int ea = csr[seg_s + p];
                    fma4(accA, bf2f((unsigned short)(ea >> 16)), hp[(ea & 0xffffu) * 16 + sub]);
                }
            }
            #pragma unroll
            for (int c = 0; c < 4; ++c) {
                accA[c] += accB[c];
                accA[c] += __shfl_xor(accA[c], 16);
                accA[c] += __shfl_xor(accA[c], 32);
            }
            if (grp == 0) {
                uint2 self = hp[(size_t)(blockIdx.x * 16 + r) * 16 + sub];
                accA[0] += bf2f((unsigned short)(self.x & 0xffff));
                accA[1] += bf2f((unsigned short)(self.x >> 16));
                accA[2] += bf2f((unsigned short)(self.y & 0xffff));
                accA[3] += bf2f((unsigned short)(self.y >> 16));
                *(uint2*)(A1 + r * 68 + sub * 2) = make_uint2(pk2(accA[0], accA[1]), pk2(accA[2], accA[3]));
            }
        } else {
            const uint4* hp = (const uint4*)h_in;
            int p = ls + grp;
            if (le <= staged) {
                for (; p + 4 < le; p += 8) {
                    unsigned int ea = scsr[p], eb = scsr[p + 4];
                    uint4 ha = hp[(ea & 0xffffu) * 16 + sub];
                    uint4 hb = hp[(eb & 0xffffu) * 16 + sub];
                    fma8(accA, bf2f((unsigned short)(ea >> 16)), ha);
                    fma8(accB, bf2f((unsigned short)(eb >> 16)), hb);
                }
                if (p < le) {
                    unsigned int ea = scsr[p];
                    fma8(accA, bf2f((unsigned short)(ea >> 16)), hp[(ea & 0xffffu) * 16 + sub]);
                }
            } else {
                for (; p < le; p += 4) {
                    unsigned int ea = csr[seg_s + p];
                    fma8(accA, bf2f((unsigned short)(ea >> 16)), hp[(ea & 0xffffu) * 16 + sub]);
                }
            }
            #pragma unroll
            for (int c = 0; c < 8; ++c) {
                accA[c] += accB[c];
                accA[c] += __shfl_xor(accA[c], 16);
                accA[c] += __shfl_xor(accA[c], 32);
            }
            if (grp == 0) {
                uint4 self = hp[(size_t)(blockIdx.x * 16 + r) * 16 + sub];
                accA[0] += bf2f((unsigned short)(self.x & 0xffff));
                accA[1] += bf2f((unsigned short)(self.x >> 16));
                accA[2] += bf2f((unsigned short)(self.y & 0xffff));
                accA[3] += bf2f((unsigned short)(self.y >> 16));
                accA[4] += bf2f((unsigned short)(self.z & 0xffff));
                accA[5] += bf2f((unsigned short)(self.z >> 16));
                accA[6] += bf2f((unsigned short)(self.w & 0xffff));
                accA[7] += bf2f((unsigned short)(self.w >> 16));
                *(uint4*)(A1 + r * 68 + sub * 4) =
                    make_uint4(pk2(accA[0], accA[1]), pk2(accA[2], accA[3]),
                               pk2(accA[4], accA[5]), pk2(accA[6], accA[7]));
            }
        }
    }
    __syncthreads();

    // ---- GEMM1: T = relu(A1 @ W1 + b1); wave computes cols wave*32..+31 ----
    const unsigned short* A1s = (const unsigned short*)A1;
    unsigned short* Ts = (unsigned short*)T;

    bf16x8 af[KS1];
    #pragma unroll
    for (int kk = 0; kk < KS1; ++kk)
        af[kk] = *(const bf16x8*)(A1s + mrow * 136 + kk * 32 + quad * 8);

    f32x4 acc1v[2];
    #pragma unroll
    for (int c = 0; c < 2; ++c) acc1v[c] = (f32x4){0.f, 0.f, 0.f, 0.f};
    #pragma unroll
    for (int c = 0; c < 2; ++c) {
        const bf16x8* Brow = (const bf16x8*)(W1t + (size_t)(wave * 32 + c * 16 + mrow) * K1);
        #pragma unroll
        for (int kk = 0; kk < KS1; ++kk)
            acc1v[c] = __builtin_amdgcn_mfma_f32_16x16x32_bf16(af[kk], Brow[kk * 4 + quad], acc1v[c], 0, 0, 0);
    }
    #pragma unroll
    for (int c = 0; c < 2; ++c) {
        int ocol = wave * 32 + c * 16 + mrow;
        float bv = b1[ocol];
        #pragma unroll
        for (int r = 0; r < 4; ++r)
            Ts[(quad * 4 + r) * 136 + ocol] = f2bf(fmaxf(acc1v[c][r] + bv, 0.f));
    }
    __syncthreads();

    // ---- GEMM2: val = T @ W2 + b2 ----
    bf16x8 a2f[4];
    #pragma unroll
    for (int kk = 0; kk < 4; ++kk)
        a2f[kk] = *(const bf16x8*)(Ts + mrow * 136 + kk * 32 + quad * 8);
    f32x4 acc2v[2];
    #pragma unroll
    for (int c = 0; c < 2; ++c) acc2v[c] = (f32x4){0.f, 0.f, 0.f, 0.f};
    #pragma unroll
    for (int c = 0; c < 2; ++c) {
        const bf16x8* Brow = (const bf16x8*)(W2t + (size_t)(wave * 32 + c * 16 + mrow) * 128);
        #pragma unroll
        for (int kk = 0; kk < 4; ++kk)
            acc2v[c] = __builtin_amdgcn_mfma_f32_16x16x32_bf16(a2f[kk], Brow[kk * 4 + quad], acc2v[c], 0, 0, 0);
    }
    __syncthreads();     // T reads done; OUT overlays A1/T

    #pragma unroll
    for (int c = 0; c < 2; ++c) {
        int ocol = wave * 32 + c * 16 + mrow;
        float bv = b2[ocol];
        #pragma unroll
        for (int r = 0; r < 4; ++r)
            OUT[(quad * 4 + r) * 132 + ocol] = acc2v[c][r] + bv;
    }
    __syncthreads();

    // ---- h_out = bn(val), bf16, coalesced (not for LAST) ----
    if (!LAST) {
        int row = tid >> 4, q = tid & 15;    // 16 rows x 16 col-groups of 8
        const float* Op = OUT + row * 132 + q * 8;
        unsigned int pk[4];
        #pragma unroll
        for (int i = 0; i < 4; ++i) {
            int c0 = q * 8 + i * 2;
            float o0 = Op[i * 2]     * sscale[c0]     + sshift[c0];
            float o1 = Op[i * 2 + 1] * sscale[c0 + 1] + sshift[c0 + 1];
            pk[i] = pk2(o0, o1);
        }
        *(uint4*)(h_out + (size_t)(blockIdx.x * 16 + row) * 128 + q * 8) =
            make_uint4(pk[0], pk[1], pk[2], pk[3]);
    }

    // ---- segmented pool (LAST pools bn'd values) ----
    {
        int col = tid & 127, half = tid >> 7;
        float sc = LAST ? sscale[col] : 1.f;
        float sh = LAST ? sshift[col] : 0.f;
        float accp = 0.f;
        int cur = sgid[half * 8];
        for (int r = half * 8; r < half * 8 + 8; ++r) {
            int gi = sgid[r];
            if (gi != cur) {
                atomicAdd(&pools[(size_t)cur * 640 + col_off + col], accp);
                accp = 0.f;
                cur = gi;
            }
            float val = OUT[r * 132 + col];
            accp += LAST ? (val * sc + sh) : val;
        }
        atomicAdd(&pools[(size_t)cur * 640 + col_off + col], accp);
    }
}

// ---------------- fused readout ----------------
__global__ __launch_bounds__(128) void readout(const float* __restrict__ pools,
                                               const float* __restrict__ Wm1,
                                               const float* __restrict__ bm1,
                                               const float* __restrict__ Wm2,
                                               const float* __restrict__ bm2,
                                               float* __restrict__ out) {
    __shared__ float row[640];
    __shared__ float partial[4];
    int gb = blockIdx.x;
    for (int k = threadIdx.x; k < 640; k += 128) row[k] = pools[(size_t)gb * 640 + k];
    __syncthreads();
    int j = threadIdx.x;
    float acc = bm1[j];
    for (int k = 0; k < 640; ++k) acc += row[k] * Wm1[(size_t)k * 128 + j];
    acc = fmaxf(acc, 0.f);
    float p0 = acc * Wm2[j * 2], p1 = acc * Wm2[j * 2 + 1];
    #pragma unroll
    for (int off = 32; off; off >>= 1) { p0 += __shfl_down(p0, off); p1 += __shfl_down(p1, off); }
    int wave = j >> 6;
    if ((j & 63) == 0) { partial[wave * 2] = p0; partial[wave * 2 + 1] = p1; }
    __syncthreads();
    if (j == 0) {
        out[gb * 2]     = bm2[0] + partial[0] + partial[2];
        out[gb * 2 + 1] = bm2[1] + partial[1] + partial[3];
    }
}

extern "C" void kernel_launch(void* const* d_in, const int* in_sizes, int n_in,
                              void* d_out, int out_size, void* d_ws, size_t ws_size,
                              hipStream_t stream) {
    const float* x  = (const float*)d_in[0];
    const float* ew = (const float*)d_in[1];
    const float *W1[5], *b1[5], *W2[5], *b2[5];
    for (int l = 0; l < 5; ++l) {
        W1[l] = (const float*)d_in[2 + 4 * l];
        b1[l] = (const float*)d_in[3 + 4 * l];
        W2[l] = (const float*)d_in[4 + 4 * l];
        b2[l] = (const float*)d_in[5 + 4 * l];
    }
    const float *bg[3], *bb[3], *bm[3], *bv[3];
    for (int j = 0; j < 3; ++j) {
        bg[j] = (const float*)d_in[22 + 4 * j];
        bb[j] = (const float*)d_in[23 + 4 * j];
        bm[j] = (const float*)d_in[24 + 4 * j];
        bv[j] = (const float*)d_in[25 + 4 * j];
    }
    const float* Wm1 = (const float*)d_in[34];
    const float* bm1 = (const float*)d_in[35];
    const float* Wm2 = (const float*)d_in[36];
    const float* bm2 = (const float*)d_in[37];
    const int* edge_index = (const int*)d_in[38];
    const int* src = edge_index;
    const int* dst = edge_index + EE;
    const int* gidx = (const int*)d_in[39];

    char* p = (char*)d_ws;
    auto alloc = [&](size_t bytes) -> void* {
        void* r = (void*)p;
        p += (bytes + 255) & ~(size_t)255;
        return r;
    };
    unsigned int* csr = (unsigned int*)alloc((size_t)EE * 4);
    int* row_start    = (int*)alloc((NN + 1) * 4);
    int* cnt          = (int*)alloc(NN * 4);
    int* cursor       = (int*)alloc(NN * 4);
    unsigned short* xb = (unsigned short*)alloc((size_t)NN * 64 * 2);
    unsigned short* hA = (unsigned short*)alloc((size_t)NN * 128 * 2);
    unsigned short* hB = (unsigned short*)alloc((size_t)NN * 128 * 2);
    float* pools = (float*)alloc((size_t)GG * 640 * 4);
    unsigned short* W1t[5], *W2t[5];
    for (int l = 0; l < 5; ++l) {
        W1t[l] = (unsigned short*)alloc((size_t)128 * 128 * 2);
        W2t[l] = (unsigned short*)alloc((size_t)128 * 128 * 2);
    }

    hipMemsetAsync(cnt, 0, NN * 4, stream);
    hipMemsetAsync(pools, 0, (size_t)GG * 640 * 4, stream);

    WJobs jobs;
    for (int l = 0; l < 5; ++l) {
        jobs.j[2 * l]     = WJob{W1[l], W1t[l], (l == 0) ? 64 : 128};
        jobs.j[2 * l + 1] = WJob{W2[l], W2t[l], 128};
    }
    prep_kernel<<<2048 + 40 + 512, 256, 0, stream>>>(jobs, src, cnt, x, xb);
    scan_kernel<<<1, 1024, 0, stream>>>(cnt, row_start, cursor);
    fill_kernel<<<EE / 256, 256, 0, stream>>>(src, dst, ew, cursor, csr);

    // bn applied AFTER layer l: {bn1, bn1, bn2, bn3, bn3}
    const int bnsel[5] = {0, 0, 1, 2, 2};

    // layer 0 (bf16 xb input, K1=64)
    layer_kernel<true, false><<<NN / 16, 256, 0, stream>>>(
        xb, row_start, csr, W1t[0], b1[0], W2t[0], b2[0],
        bg[0], bb[0], bm[0], bv[0], gidx, hA, pools, 0);

    const unsigned short* hin = hA;
    unsigned short* hout = hB;
    for (int l = 1; l < 5; ++l) {
        int s = bnsel[l];
        if (l < 4) {
            layer_kernel<false, false><<<NN / 16, 256, 0, stream>>>(
                hin, row_start, csr, W1t[l], b1[l], W2t[l], b2[l],
                bg[s], bb[s], bm[s], bv[s], gidx, hout, pools, l * 128);
        } else {
            layer_kernel<false, true><<<NN / 16, 256, 0, stream>>>(
                hin, row_start, csr, W1t[l], b1[l], W2t[l], b2[l],
                bg[s], bb[s], bm[s], bv[s], gidx, hout, pools, l * 128);
        }
        unsigned short* tmp = (unsigned short*)hin;
        hin = hout;
        hout = tmp;
    }

    readout<<<GG, 128, 0, stream>>>(pools, Wm1, bm1, Wm2, bm2, (float*)d_out);
}